// Round 1
// baseline (55.944 us; speedup 1.0000x reference)
//
#include <hip/hip_runtime.h>
#include <hip/hip_bf16.h>
#include <math.h>

// Problem constants (from reference setup_inputs)
#define B 8
#define S 512
#define G 16
#define DA 1024
#define DM 256
#define WIN 12

__inline__ __device__ float waveReduceSum(float v) {
#pragma unroll
    for (int o = 32; o > 0; o >>= 1) v += __shfl_xor(v, o, 64);
    return v;
}

// 256 threads = 4 waves. Returns full sum (broadcast to all threads).
__inline__ __device__ float blockReduceSum(float v, float* s4) {
    int lane = threadIdx.x & 63, wid = threadIdx.x >> 6;
    v = waveReduceSum(v);
    __syncthreads();
    if (lane == 0) s4[wid] = v;
    __syncthreads();
    return s4[0] + s4[1] + s4[2] + s4[3];
}

// K1: per-(b,s) row projections.
// proj0a[b,s] = att[b,s]·W_att[0:DA]     proj2a[b,s] = att[b,s]·W_att[2DA:3DA]
// proj0m[b,s] = mod[b,s]·W_mod[0:DM]     proj2m[b,s] = mod[b,s]·W_mod[2DM:3DM]
__global__ __launch_bounds__(256) void k_proj(
    const float* __restrict__ att, const float* __restrict__ mod,
    const float* __restrict__ Wa, const float* __restrict__ Wm,
    float* __restrict__ proj0a, float* __restrict__ proj2a,
    float* __restrict__ proj0m, float* __restrict__ proj2m)
{
    __shared__ float s4[4];
    const int s = blockIdx.x, b = blockIdx.y, t = threadIdx.x;
    const int row = b * S + s;

    const float4* arow = (const float4*)(att + (size_t)row * DA);
    const float4* W0 = (const float4*)Wa;              // W_att[0:1024)
    const float4* W2 = (const float4*)(Wa + 2 * DA);   // W_att[2048:3072)
    float4 va = arow[t];
    float4 w0 = W0[t];
    float4 w2 = W2[t];
    float p0 = va.x * w0.x + va.y * w0.y + va.z * w0.z + va.w * w0.w;
    float p2 = va.x * w2.x + va.y * w2.y + va.z * w2.z + va.w * w2.w;

    float vm = mod[(size_t)row * DM + t];
    float q0 = vm * Wm[t];            // W_mod[0:256)
    float q2 = vm * Wm[2 * DM + t];   // W_mod[512:768)

    p0 = blockReduceSum(p0, s4);
    p2 = blockReduceSum(p2, s4);
    q0 = blockReduceSum(q0, s4);
    q2 = blockReduceSum(q2, s4);
    if (t == 0) {
        proj0a[row] = p0;
        proj2a[row] = p2;
        proj0m[row] = q0;
        proj2m[row] = q2;
    }
}

// K2: global (unmasked) max over s per d, dotted with max-slice weights.
// blockIdx.x = c: c<4 -> att d-chunk c (256 d's), c==4 -> mod (256 d's).
__global__ __launch_bounds__(256) void k_gmax(
    const float* __restrict__ att, const float* __restrict__ mod,
    const float* __restrict__ Wa, const float* __restrict__ Wm,
    float* __restrict__ pg_att, float* __restrict__ pg_mod)
{
    __shared__ float s4[4];
    const int c = blockIdx.x, b = blockIdx.y, t = threadIdx.x;
    float partial;
    if (c < 4) {
        const int d = c * 256 + t;
        const float* base = att + (size_t)b * S * DA + d;
        float m = -INFINITY;
        for (int s = 0; s < S; s += 4) {
            float a0 = base[(size_t)(s + 0) * DA];
            float a1 = base[(size_t)(s + 1) * DA];
            float a2 = base[(size_t)(s + 2) * DA];
            float a3 = base[(size_t)(s + 3) * DA];
            m = fmaxf(m, fmaxf(fmaxf(a0, a1), fmaxf(a2, a3)));
        }
        partial = Wa[DA + d] * m;   // W_att[1024+d]
    } else {
        const int d = t;
        const float* base = mod + (size_t)b * S * DM + d;
        float m = -INFINITY;
        for (int s = 0; s < S; s += 4) {
            float a0 = base[(size_t)(s + 0) * DM];
            float a1 = base[(size_t)(s + 1) * DM];
            float a2 = base[(size_t)(s + 2) * DM];
            float a3 = base[(size_t)(s + 3) * DM];
            m = fmaxf(m, fmaxf(fmaxf(a0, a1), fmaxf(a2, a3)));
        }
        partial = Wm[DM + d] * m;   // W_mod[256+d]
    }
    partial = blockReduceSum(partial, s4);
    if (t == 0) {
        if (c < 4) pg_att[b * 4 + c] = partial;
        else       pg_mod[b] = partial;
    }
}

// K3: one block per output logit (g, b).
__global__ __launch_bounds__(256) void k_final(
    const float* __restrict__ att, const float* __restrict__ mod,
    const float* __restrict__ Wa, const float* __restrict__ Wm,
    const float* __restrict__ ba, const float* __restrict__ bm,
    const int* __restrict__ gidx, const int* __restrict__ mask,
    const float* __restrict__ proj0a, const float* __restrict__ proj2a,
    const float* __restrict__ proj0m, const float* __restrict__ proj2m,
    const float* __restrict__ pg_att, const float* __restrict__ pg_mod,
    float* __restrict__ out)
{
    __shared__ float s4[4];
    const int g = blockIdx.x, b = blockIdx.y, t = threadIdx.x;
    const int gi = gidx[b * G + g];

    if (g == 0) {
        // Global pools row: avg = (sum over ALL s of proj2) / (sum of mask)
        float sa = 0.f, sm = 0.f, cm = 0.f;
        for (int s = t; s < S; s += 256) {
            sa += proj2a[b * S + s];
            sm += proj2m[b * S + s];
            cm += (float)mask[b * S + s];
        }
        sa = blockReduceSum(sa, s4);
        sm = blockReduceSum(sm, s4);
        cm = blockReduceSum(cm, s4);
        if (t == 0) {
            float gt = pg_att[b * 4 + 0] + pg_att[b * 4 + 1] +
                       pg_att[b * 4 + 2] + pg_att[b * 4 + 3] + pg_mod[b];
            float res = proj0a[b * S + gi] + proj0m[b * S + gi] + gt +
                        sa / cm + sm / cm + ba[0] + bm[0];
            out[b * G + 0] = res;
        }
    } else {
        int lo = gi - WIN; if (lo < 0) lo = 0;
        int hi = gi + WIN; if (hi > S - 1) hi = S - 1;

        // Per-d windowed max (clamped at 0: out-of-window entries contribute 0
        // to the reference's max over x*wmf, and 25 < 512 always leaves zeros).
        float4 m4 = make_float4(0.f, 0.f, 0.f, 0.f);
        float mm = 0.f;
        const float4* a4 = (const float4*)att;
        for (int s = lo; s <= hi; ++s) {
            if (mask[b * S + s] > 0) {
                float4 v = a4[(size_t)(b * S + s) * (DA / 4) + t];
                m4.x = fmaxf(m4.x, v.x);
                m4.y = fmaxf(m4.y, v.y);
                m4.z = fmaxf(m4.z, v.z);
                m4.w = fmaxf(m4.w, v.w);
                mm = fmaxf(mm, mod[(size_t)(b * S + s) * DM + t]);
            }
        }
        const float4* W1a4 = (const float4*)(Wa + DA);
        float4 w = W1a4[t];
        float pa = m4.x * w.x + m4.y * w.y + m4.z * w.z + m4.w * w.w;
        float pm = Wm[DM + t] * mm;

        // Windowed proj2 sums + count
        float sa = 0.f, sm = 0.f, cn = 0.f;
        int s = lo + t;
        if (s <= hi && mask[b * S + s] > 0) {
            sa = proj2a[b * S + s];
            sm = proj2m[b * S + s];
            cn = 1.f;
        }
        pa = blockReduceSum(pa, s4);
        pm = blockReduceSum(pm, s4);
        sa = blockReduceSum(sa, s4);
        sm = blockReduceSum(sm, s4);
        cn = blockReduceSum(cn, s4);
        if (t == 0) {
            float res = proj0a[b * S + gi] + proj0m[b * S + gi] +
                        pa + pm + sa / cn + sm / cn + ba[0] + bm[0];
            out[b * G + g] = res;
        }
    }
}

extern "C" void kernel_launch(void* const* d_in, const int* in_sizes, int n_in,
                              void* d_out, int out_size, void* d_ws, size_t ws_size,
                              hipStream_t stream) {
    const float* att  = (const float*)d_in[0];
    const float* mod  = (const float*)d_in[1];
    const float* Wa   = (const float*)d_in[2];
    const float* ba   = (const float*)d_in[3];
    const float* Wm   = (const float*)d_in[4];
    const float* bm   = (const float*)d_in[5];
    // d_in[6] = q_enc (unused by reference)
    const int* gidx   = (const int*)d_in[7];
    const int* mask   = (const int*)d_in[8];
    // d_in[9] = q_mask (unused by reference)
    float* out = (float*)d_out;

    // Workspace layout (floats)
    float* ws     = (float*)d_ws;
    float* proj0a = ws;                 // B*S
    float* proj2a = proj0a + B * S;     // B*S
    float* proj0m = proj2a + B * S;     // B*S
    float* proj2m = proj0m + B * S;     // B*S
    float* pg_att = proj2m + B * S;     // B*4
    float* pg_mod = pg_att + B * 4;     // B

    k_proj<<<dim3(S, B), 256, 0, stream>>>(att, mod, Wa, Wm,
                                           proj0a, proj2a, proj0m, proj2m);
    k_gmax<<<dim3(5, B), 256, 0, stream>>>(att, mod, Wa, Wm, pg_att, pg_mod);
    k_final<<<dim3(G, B), 256, 0, stream>>>(att, mod, Wa, Wm, ba, bm, gidx, mask,
                                            proj0a, proj2a, proj0m, proj2m,
                                            pg_att, pg_mod, out);
}

// Round 2
// 28.660 us; speedup vs baseline: 1.9520x; 1.9520x over previous
//
#include <hip/hip_runtime.h>
#include <hip/hip_bf16.h>
#include <math.h>

// Problem constants (from reference setup_inputs)
#define B 8
#define S 512
#define G 16
#define DA 1024
#define DM 256
#define WIN 12
#define NCHUNK 16                 // s-chunks for partial max
#define ROWS (S / NCHUNK)         // 32 rows per chunk
#define DTOT (DA + DM)            // 1280 pooled dims

__inline__ __device__ float waveReduceSum(float v) {
#pragma unroll
    for (int o = 32; o > 0; o >>= 1) v += __shfl_xor(v, o, 64);
    return v;
}

// 256 threads = 4 waves. One LDS round, returns full sum broadcast.
__inline__ __device__ float blockReduceSum(float v, float* s4) {
    int lane = threadIdx.x & 63, wid = threadIdx.x >> 6;
    v = waveReduceSum(v);
    __syncthreads();
    if (lane == 0) s4[wid] = v;
    __syncthreads();
    return s4[0] + s4[1] + s4[2] + s4[3];
}

// Batched: reduce 4 scalars in one LDS round.
__inline__ __device__ float4 blockReduceSum4(float4 v, float4* s4) {
    int lane = threadIdx.x & 63, wid = threadIdx.x >> 6;
#pragma unroll
    for (int o = 32; o > 0; o >>= 1) {
        v.x += __shfl_xor(v.x, o, 64);
        v.y += __shfl_xor(v.y, o, 64);
        v.z += __shfl_xor(v.z, o, 64);
        v.w += __shfl_xor(v.w, o, 64);
    }
    __syncthreads();
    if (lane == 0) s4[wid] = v;
    __syncthreads();
    float4 r;
    r.x = s4[0].x + s4[1].x + s4[2].x + s4[3].x;
    r.y = s4[0].y + s4[1].y + s4[2].y + s4[3].y;
    r.z = s4[0].z + s4[1].z + s4[2].z + s4[3].z;
    r.w = s4[0].w + s4[1].w + s4[2].w + s4[3].w;
    return r;
}

// K1: per-(b,s) row projections (one block per row).
// proj0a[b,s] = att[b,s]·W_att[0:DA]     proj2a[b,s] = att[b,s]·W_att[2DA:3DA]
// proj0m[b,s] = mod[b,s]·W_mod[0:DM]     proj2m[b,s] = mod[b,s]·W_mod[2DM:3DM]
__global__ __launch_bounds__(256) void k_proj(
    const float* __restrict__ att, const float* __restrict__ mod,
    const float* __restrict__ Wa, const float* __restrict__ Wm,
    float* __restrict__ proj0a, float* __restrict__ proj2a,
    float* __restrict__ proj0m, float* __restrict__ proj2m)
{
    __shared__ float4 s4[4];
    const int s = blockIdx.x, b = blockIdx.y, t = threadIdx.x;
    const int row = b * S + s;

    const float4* arow = (const float4*)(att + (size_t)row * DA);
    const float4* W0 = (const float4*)Wa;              // W_att[0:1024)
    const float4* W2 = (const float4*)(Wa + 2 * DA);   // W_att[2048:3072)
    float4 va = arow[t];
    float4 w0 = W0[t];
    float4 w2 = W2[t];
    float p0 = va.x * w0.x + va.y * w0.y + va.z * w0.z + va.w * w0.w;
    float p2 = va.x * w2.x + va.y * w2.y + va.z * w2.z + va.w * w2.w;

    float vm = mod[(size_t)row * DM + t];
    float q0 = vm * Wm[t];            // W_mod[0:256)
    float q2 = vm * Wm[2 * DM + t];   // W_mod[512:768)

    float4 r = blockReduceSum4(make_float4(p0, p2, q0, q2), s4);
    if (t == 0) {
        proj0a[row] = r.x;
        proj2a[row] = r.y;
        proj0m[row] = r.z;
        proj2m[row] = r.w;
    }
}

// K2: partial per-d max over an s-chunk. Pure streaming, no reductions.
// grid (5, NCHUNK, B): c<4 -> att d-chunk c (256 d's), c==4 -> mod.
// pmax[b][chunk][d] with d in [0,1280): 0..1023 att, 1024..1279 mod.
__global__ __launch_bounds__(256) void k_pmax(
    const float* __restrict__ att, const float* __restrict__ mod,
    float* __restrict__ pmax)
{
    const int c = blockIdx.x, ch = blockIdx.y, b = blockIdx.z, t = threadIdx.x;
    const int s0 = ch * ROWS;
    float m0 = -INFINITY, m1 = -INFINITY, m2 = -INFINITY, m3 = -INFINITY;
    if (c < 4) {
        const int d = c * 256 + t;
        const float* base = att + ((size_t)b * S + s0) * DA + d;
#pragma unroll
        for (int s = 0; s < ROWS; s += 4) {
            m0 = fmaxf(m0, base[(size_t)(s + 0) * DA]);
            m1 = fmaxf(m1, base[(size_t)(s + 1) * DA]);
            m2 = fmaxf(m2, base[(size_t)(s + 2) * DA]);
            m3 = fmaxf(m3, base[(size_t)(s + 3) * DA]);
        }
        pmax[((size_t)b * NCHUNK + ch) * DTOT + d] =
            fmaxf(fmaxf(m0, m1), fmaxf(m2, m3));
    } else {
        const int d = t;
        const float* base = mod + ((size_t)b * S + s0) * DM + d;
#pragma unroll
        for (int s = 0; s < ROWS; s += 4) {
            m0 = fmaxf(m0, base[(size_t)(s + 0) * DM]);
            m1 = fmaxf(m1, base[(size_t)(s + 1) * DM]);
            m2 = fmaxf(m2, base[(size_t)(s + 2) * DM]);
            m3 = fmaxf(m3, base[(size_t)(s + 3) * DM]);
        }
        pmax[((size_t)b * NCHUNK + ch) * DTOT + DA + d] =
            fmaxf(fmaxf(m0, m1), fmaxf(m2, m3));
    }
}

// K3: one block per output logit (g, b).
__global__ __launch_bounds__(256) void k_final(
    const float* __restrict__ att, const float* __restrict__ mod,
    const float* __restrict__ Wa, const float* __restrict__ Wm,
    const float* __restrict__ ba, const float* __restrict__ bm,
    const int* __restrict__ gidx, const int* __restrict__ mask,
    const float* __restrict__ proj0a, const float* __restrict__ proj2a,
    const float* __restrict__ proj0m, const float* __restrict__ proj2m,
    const float* __restrict__ pmax,
    float* __restrict__ out)
{
    __shared__ float4 s4[4];
    __shared__ float s1[4];
    const int g = blockIdx.x, b = blockIdx.y, t = threadIdx.x;
    const int gi = gidx[b * G + g];

    if (g == 0) {
        // Global row: unmasked sums of proj2, mask count, and max-dot from pmax.
        float sa = 0.f, sm = 0.f, cm = 0.f;
        for (int s = t; s < S; s += 256) {
            sa += proj2a[b * S + s];
            sm += proj2m[b * S + s];
            cm += (float)mask[b * S + s];
        }
        // Reduce NCHUNK partial maxes per d, dot with max-slice weights.
        float gm = 0.f;
        for (int d = t; d < DTOT; d += 256) {
            float m = -INFINITY;
#pragma unroll
            for (int ch = 0; ch < NCHUNK; ++ch)
                m = fmaxf(m, pmax[((size_t)b * NCHUNK + ch) * DTOT + d]);
            float w = (d < DA) ? Wa[DA + d] : Wm[DM + (d - DA)];
            gm += w * m;
        }
        float4 r = blockReduceSum4(make_float4(sa, sm, cm, gm), s4);
        if (t == 0) {
            float res = proj0a[b * S + gi] + proj0m[b * S + gi] + r.w +
                        r.x / r.z + r.y / r.z + ba[0] + bm[0];
            out[b * G + 0] = res;
        }
    } else {
        int lo = gi - WIN; if (lo < 0) lo = 0;
        int hi = gi + WIN; if (hi > S - 1) hi = S - 1;

        // Per-d windowed max (clamped at 0: out-of-window entries contribute 0
        // to the reference's max over x*wmf, and 25 < 512 always leaves zeros).
        float4 m4 = make_float4(0.f, 0.f, 0.f, 0.f);
        float mm = 0.f;
        const float4* a4 = (const float4*)att;
        for (int s = lo; s <= hi; ++s) {
            if (mask[b * S + s] > 0) {
                float4 v = a4[(size_t)(b * S + s) * (DA / 4) + t];
                m4.x = fmaxf(m4.x, v.x);
                m4.y = fmaxf(m4.y, v.y);
                m4.z = fmaxf(m4.z, v.z);
                m4.w = fmaxf(m4.w, v.w);
                mm = fmaxf(mm, mod[(size_t)(b * S + s) * DM + t]);
            }
        }
        const float4* W1a4 = (const float4*)(Wa + DA);
        float4 w = W1a4[t];
        float pa = m4.x * w.x + m4.y * w.y + m4.z * w.z + m4.w * w.w;
        float pm = Wm[DM + t] * mm;

        // Windowed proj2 sums + count
        float sa = 0.f, sm = 0.f, cn = 0.f;
        int s = lo + t;
        if (s <= hi && mask[b * S + s] > 0) {
            sa = proj2a[b * S + s];
            sm = proj2m[b * S + s];
            cn = 1.f;
        }
        float4 r = blockReduceSum4(make_float4(pa, pm, sa, sm), s4);
        cn = blockReduceSum(cn, s1);
        if (t == 0) {
            float res = proj0a[b * S + gi] + proj0m[b * S + gi] +
                        r.x + r.y + r.z / cn + r.w / cn + ba[0] + bm[0];
            out[b * G + g] = res;
        }
    }
}

extern "C" void kernel_launch(void* const* d_in, const int* in_sizes, int n_in,
                              void* d_out, int out_size, void* d_ws, size_t ws_size,
                              hipStream_t stream) {
    const float* att  = (const float*)d_in[0];
    const float* mod  = (const float*)d_in[1];
    const float* Wa   = (const float*)d_in[2];
    const float* ba   = (const float*)d_in[3];
    const float* Wm   = (const float*)d_in[4];
    const float* bm   = (const float*)d_in[5];
    // d_in[6] = q_enc (unused by reference)
    const int* gidx   = (const int*)d_in[7];
    const int* mask   = (const int*)d_in[8];
    // d_in[9] = q_mask (unused by reference)
    float* out = (float*)d_out;

    // Workspace layout (floats)
    float* ws     = (float*)d_ws;
    float* proj0a = ws;                 // B*S
    float* proj2a = proj0a + B * S;     // B*S
    float* proj0m = proj2a + B * S;     // B*S
    float* proj2m = proj0m + B * S;     // B*S
    float* pmax   = proj2m + B * S;     // B*NCHUNK*DTOT

    k_proj<<<dim3(S, B), 256, 0, stream>>>(att, mod, Wa, Wm,
                                           proj0a, proj2a, proj0m, proj2m);
    k_pmax<<<dim3(5, NCHUNK, B), 256, 0, stream>>>(att, mod, pmax);
    k_final<<<dim3(G, B), 256, 0, stream>>>(att, mod, Wa, Wm, ba, bm, gidx, mask,
                                            proj0a, proj2a, proj0m, proj2m,
                                            pmax, out);
}

// Round 3
// 24.897 us; speedup vs baseline: 2.2470x; 1.1511x over previous
//
#include <hip/hip_runtime.h>
#include <hip/hip_bf16.h>
#include <math.h>

// Problem constants (from reference setup_inputs)
#define B 8
#define S 512
#define G 16
#define DA 1024
#define DM 256
#define WIN 12
#define NCHUNK 16                 // s-chunks for partial max
#define ROWS (S / NCHUNK)         // 32 rows per chunk
#define DTOT (DA + DM)            // 1280 pooled dims
#define NW 8                      // waves per fused block (512 threads)

__inline__ __device__ float waveReduceSum(float v) {
#pragma unroll
    for (int o = 32; o > 0; o >>= 1) v += __shfl_xor(v, o, 64);
    return v;
}

__inline__ __device__ float blockReduceSum(float v, float* s4) {
    int lane = threadIdx.x & 63, wid = threadIdx.x >> 6;
    v = waveReduceSum(v);
    __syncthreads();
    if (lane == 0) s4[wid] = v;
    __syncthreads();
    return s4[0] + s4[1] + s4[2] + s4[3];
}

__inline__ __device__ float4 blockReduceSum4(float4 v, float4* s4) {
    int lane = threadIdx.x & 63, wid = threadIdx.x >> 6;
#pragma unroll
    for (int o = 32; o > 0; o >>= 1) {
        v.x += __shfl_xor(v.x, o, 64);
        v.y += __shfl_xor(v.y, o, 64);
        v.z += __shfl_xor(v.z, o, 64);
        v.w += __shfl_xor(v.w, o, 64);
    }
    __syncthreads();
    if (lane == 0) s4[wid] = v;
    __syncthreads();
    float4 r;
    r.x = s4[0].x + s4[1].x + s4[2].x + s4[3].x;
    r.y = s4[0].y + s4[1].y + s4[2].y + s4[3].y;
    r.z = s4[0].z + s4[1].z + s4[2].z + s4[3].z;
    r.w = s4[0].w + s4[1].w + s4[2].w + s4[3].w;
    return r;
}

__inline__ __device__ float4 fmax4(float4 a, float4 b) {
    return make_float4(fmaxf(a.x, b.x), fmaxf(a.y, b.y),
                       fmaxf(a.z, b.z), fmaxf(a.w, b.w));
}
__inline__ __device__ float dot4(float4 a, float4 b) {
    return a.x * b.x + a.y * b.y + a.z * b.z + a.w * b.w;
}

// Fused K1: single sweep over att+mod producing per-row projections AND
// per-(b,chunk,d) partial maxes. Grid (NCHUNK, B), block 512 = 8 waves.
// Wave w owns rows [ch*ROWS + 4w, ch*ROWS + 4w + 3].
__global__ __launch_bounds__(512) void k_fused(
    const float* __restrict__ att, const float* __restrict__ mod,
    const float* __restrict__ Wa, const float* __restrict__ Wm,
    float* __restrict__ proj0a, float* __restrict__ proj2a,
    float* __restrict__ proj0m, float* __restrict__ proj2m,
    float* __restrict__ pmax)
{
    __shared__ float part[NW][DTOT];   // 8 x 1280 floats = 40 KB
    const int ch = blockIdx.x, b = blockIdx.y;
    const int t = threadIdx.x, lane = t & 63, w = t >> 6;

    // Weights held in registers for the 4-row loop.
    const float4* W0 = (const float4*)Wa;             // W_att[0:1024)
    const float4* W2 = (const float4*)(Wa + 2 * DA);  // W_att[2048:3072)
    float4 w0[4], w2[4];
#pragma unroll
    for (int k = 0; k < 4; ++k) {
        w0[k] = W0[lane + 64 * k];
        w2[k] = W2[lane + 64 * k];
    }
    const float4 wq0 = ((const float4*)Wm)[lane];             // W_mod[0:256)
    const float4 wq2 = ((const float4*)(Wm + 2 * DM))[lane];  // W_mod[512:768)

    float4 amax[4], mmax;
#pragma unroll
    for (int k = 0; k < 4; ++k)
        amax[k] = make_float4(-INFINITY, -INFINITY, -INFINITY, -INFINITY);
    mmax = make_float4(-INFINITY, -INFINITY, -INFINITY, -INFINITY);

    const int srow0 = ch * ROWS + w * 4;
#pragma unroll
    for (int r = 0; r < 4; ++r) {
        const int row = b * S + srow0 + r;
        const float4* arow = (const float4*)(att + (size_t)row * DA);
        float p0 = 0.f, p2 = 0.f;
#pragma unroll
        for (int k = 0; k < 4; ++k) {
            float4 va = arow[lane + 64 * k];
            p0 += dot4(va, w0[k]);
            p2 += dot4(va, w2[k]);
            amax[k] = fmax4(amax[k], va);
        }
        float4 vm = ((const float4*)(mod + (size_t)row * DM))[lane];
        float q0 = dot4(vm, wq0);
        float q2 = dot4(vm, wq2);
        mmax = fmax4(mmax, vm);

        // Wave-level reduce of the 4 dot partials (no __syncthreads).
#pragma unroll
        for (int o = 32; o > 0; o >>= 1) {
            p0 += __shfl_xor(p0, o, 64);
            p2 += __shfl_xor(p2, o, 64);
            q0 += __shfl_xor(q0, o, 64);
            q2 += __shfl_xor(q2, o, 64);
        }
        if (lane == 0) {
            proj0a[row] = p0;
            proj2a[row] = p2;
            proj0m[row] = q0;
            proj2m[row] = q2;
        }
    }

    // Publish per-wave partial maxes: att d = 4*(lane+64k)+{0..3}, mod d-DA = 4*lane+{0..3}
    float4* pr = (float4*)&part[w][0];
#pragma unroll
    for (int k = 0; k < 4; ++k) pr[lane + 64 * k] = amax[k];
    ((float4*)&part[w][DA])[lane] = mmax;
    __syncthreads();

    // Cross-wave max reduce; stride DTOT=1280 ≡ 0 mod 32 banks -> conflict-free.
    for (int d = t; d < DTOT; d += 512) {
        float m = part[0][d];
#pragma unroll
        for (int ww = 1; ww < NW; ++ww) m = fmaxf(m, part[ww][d]);
        pmax[((size_t)b * NCHUNK + ch) * DTOT + d] = m;
    }
}

// K3: one block per output logit (g, b).
__global__ __launch_bounds__(256) void k_final(
    const float* __restrict__ att, const float* __restrict__ mod,
    const float* __restrict__ Wa, const float* __restrict__ Wm,
    const float* __restrict__ ba, const float* __restrict__ bm,
    const int* __restrict__ gidx, const int* __restrict__ mask,
    const float* __restrict__ proj0a, const float* __restrict__ proj2a,
    const float* __restrict__ proj0m, const float* __restrict__ proj2m,
    const float* __restrict__ pmax,
    float* __restrict__ out)
{
    __shared__ float4 s4[4];
    __shared__ float s1[4];
    const int g = blockIdx.x, b = blockIdx.y, t = threadIdx.x;
    const int gi = gidx[b * G + g];

    if (g == 0) {
        // Global row: unmasked sums of proj2, mask count, and max-dot from pmax.
        float sa = 0.f, sm = 0.f, cm = 0.f;
        for (int s = t; s < S; s += 256) {
            sa += proj2a[b * S + s];
            sm += proj2m[b * S + s];
            cm += (float)mask[b * S + s];
        }
        float gm = 0.f;
        for (int d = t; d < DTOT; d += 256) {
            float m = -INFINITY;
#pragma unroll
            for (int ch = 0; ch < NCHUNK; ++ch)
                m = fmaxf(m, pmax[((size_t)b * NCHUNK + ch) * DTOT + d]);
            float wgt = (d < DA) ? Wa[DA + d] : Wm[DM + (d - DA)];
            gm += wgt * m;
        }
        float4 r = blockReduceSum4(make_float4(sa, sm, cm, gm), s4);
        if (t == 0) {
            float res = proj0a[b * S + gi] + proj0m[b * S + gi] + r.w +
                        r.x / r.z + r.y / r.z + ba[0] + bm[0];
            out[b * G + 0] = res;
        }
    } else {
        int lo = gi - WIN; if (lo < 0) lo = 0;
        int hi = gi + WIN; if (hi > S - 1) hi = S - 1;

        // Per-d windowed max (clamped at 0: out-of-window entries contribute 0
        // to the reference's max over x*wmf, and 25 < 512 always leaves zeros).
        float4 m4 = make_float4(0.f, 0.f, 0.f, 0.f);
        float mm = 0.f;
        const float4* a4 = (const float4*)att;
        for (int s = lo; s <= hi; ++s) {
            if (mask[b * S + s] > 0) {
                float4 v = a4[(size_t)(b * S + s) * (DA / 4) + t];
                m4.x = fmaxf(m4.x, v.x);
                m4.y = fmaxf(m4.y, v.y);
                m4.z = fmaxf(m4.z, v.z);
                m4.w = fmaxf(m4.w, v.w);
                mm = fmaxf(mm, mod[(size_t)(b * S + s) * DM + t]);
            }
        }
        const float4* W1a4 = (const float4*)(Wa + DA);
        float4 w = W1a4[t];
        float pa = dot4(m4, w);
        float pm = Wm[DM + t] * mm;

        // Windowed proj2 sums + count
        float sa = 0.f, sm = 0.f, cn = 0.f;
        int s = lo + t;
        if (s <= hi && mask[b * S + s] > 0) {
            sa = proj2a[b * S + s];
            sm = proj2m[b * S + s];
            cn = 1.f;
        }
        float4 r = blockReduceSum4(make_float4(pa, pm, sa, sm), s4);
        cn = blockReduceSum(cn, s1);
        if (t == 0) {
            float res = proj0a[b * S + gi] + proj0m[b * S + gi] +
                        r.x + r.y + r.z / cn + r.w / cn + ba[0] + bm[0];
            out[b * G + g] = res;
        }
    }
}

extern "C" void kernel_launch(void* const* d_in, const int* in_sizes, int n_in,
                              void* d_out, int out_size, void* d_ws, size_t ws_size,
                              hipStream_t stream) {
    const float* att  = (const float*)d_in[0];
    const float* mod  = (const float*)d_in[1];
    const float* Wa   = (const float*)d_in[2];
    const float* ba   = (const float*)d_in[3];
    const float* Wm   = (const float*)d_in[4];
    const float* bm   = (const float*)d_in[5];
    // d_in[6] = q_enc (unused by reference)
    const int* gidx   = (const int*)d_in[7];
    const int* mask   = (const int*)d_in[8];
    // d_in[9] = q_mask (unused by reference)
    float* out = (float*)d_out;

    // Workspace layout (floats)
    float* ws     = (float*)d_ws;
    float* proj0a = ws;                 // B*S
    float* proj2a = proj0a + B * S;     // B*S
    float* proj0m = proj2a + B * S;     // B*S
    float* proj2m = proj0m + B * S;     // B*S
    float* pmax   = proj2m + B * S;     // B*NCHUNK*DTOT

    k_fused<<<dim3(NCHUNK, B), 512, 0, stream>>>(att, mod, Wa, Wm,
                                                 proj0a, proj2a, proj0m, proj2m,
                                                 pmax);
    k_final<<<dim3(G, B), 256, 0, stream>>>(att, mod, Wa, Wm, ba, bm, gidx, mask,
                                            proj0a, proj2a, proj0m, proj2m,
                                            pmax, out);
}

// Round 4
// 18.866 us; speedup vs baseline: 2.9653x; 1.3197x over previous
//
#include <hip/hip_runtime.h>
#include <hip/hip_bf16.h>
#include <math.h>

// Problem constants (from reference setup_inputs)
#define B 8
#define S 512
#define G 16
#define DA 1024
#define DM 256
#define WIN 12
#define NCHUNK 32                 // s-chunks for partial max (256 blocks)
#define ROWS (S / NCHUNK)         // 16 rows per chunk
#define DTOT (DA + DM)            // 1280 pooled dims
#define NW 8                      // waves per fused block (512 threads)
#define RPW (ROWS / NW)           // 2 rows per wave

__inline__ __device__ float4 fmax4(float4 a, float4 b) {
    return make_float4(fmaxf(a.x, b.x), fmaxf(a.y, b.y),
                       fmaxf(a.z, b.z), fmaxf(a.w, b.w));
}
__inline__ __device__ float dot4(float4 a, float4 b) {
    return a.x * b.x + a.y * b.y + a.z * b.z + a.w * b.w;
}

// 16-wave (1024-thread) batched block reduce: 4 sums in one LDS round.
__inline__ __device__ float4 blockReduceSum4_16(float4 v, float4* sh) {
    int lane = threadIdx.x & 63, w = threadIdx.x >> 6;
#pragma unroll
    for (int o = 32; o > 0; o >>= 1) {
        v.x += __shfl_xor(v.x, o, 64);
        v.y += __shfl_xor(v.y, o, 64);
        v.z += __shfl_xor(v.z, o, 64);
        v.w += __shfl_xor(v.w, o, 64);
    }
    __syncthreads();
    if (lane == 0) sh[w] = v;
    __syncthreads();
    float4 r = sh[0];
#pragma unroll
    for (int ww = 1; ww < 16; ++ww) {
        r.x += sh[ww].x; r.y += sh[ww].y; r.z += sh[ww].z; r.w += sh[ww].w;
    }
    return r;
}

__inline__ __device__ float blockReduceSum_16(float v, float* sh) {
    int lane = threadIdx.x & 63, w = threadIdx.x >> 6;
#pragma unroll
    for (int o = 32; o > 0; o >>= 1) v += __shfl_xor(v, o, 64);
    __syncthreads();
    if (lane == 0) sh[w] = v;
    __syncthreads();
    float r = sh[0];
#pragma unroll
    for (int ww = 1; ww < 16; ++ww) r += sh[ww];
    return r;
}

// Fused K1: single sweep over att+mod producing per-row projections AND
// per-(b,chunk,d) partial maxes. Grid (NCHUNK, B) = 256 blocks, 512 thr.
// Wave w owns rows [ch*ROWS + RPW*w, ch*ROWS + RPW*w + RPW).
__global__ __launch_bounds__(512) void k_fused(
    const float* __restrict__ att, const float* __restrict__ mod,
    const float* __restrict__ Wa, const float* __restrict__ Wm,
    float* __restrict__ proj0a, float* __restrict__ proj2a,
    float* __restrict__ proj0m, float* __restrict__ proj2m,
    float* __restrict__ pmax)
{
    __shared__ float part[NW][DTOT];   // 8 x 1280 floats = 40 KB
    const int ch = blockIdx.x, b = blockIdx.y;
    const int t = threadIdx.x, lane = t & 63, w = t >> 6;

    // Weights held in registers for the row loop.
    const float4* W0 = (const float4*)Wa;             // W_att[0:1024)
    const float4* W2 = (const float4*)(Wa + 2 * DA);  // W_att[2048:3072)
    float4 w0[4], w2[4];
#pragma unroll
    for (int k = 0; k < 4; ++k) {
        w0[k] = W0[lane + 64 * k];
        w2[k] = W2[lane + 64 * k];
    }
    const float4 wq0 = ((const float4*)Wm)[lane];             // W_mod[0:256)
    const float4 wq2 = ((const float4*)(Wm + 2 * DM))[lane];  // W_mod[512:768)

    float4 amax[4], mmax;
#pragma unroll
    for (int k = 0; k < 4; ++k)
        amax[k] = make_float4(-INFINITY, -INFINITY, -INFINITY, -INFINITY);
    mmax = make_float4(-INFINITY, -INFINITY, -INFINITY, -INFINITY);

    const int srow0 = ch * ROWS + w * RPW;
#pragma unroll
    for (int r = 0; r < RPW; ++r) {
        const int row = b * S + srow0 + r;
        const float4* arow = (const float4*)(att + (size_t)row * DA);
        float p0 = 0.f, p2 = 0.f;
#pragma unroll
        for (int k = 0; k < 4; ++k) {
            float4 va = arow[lane + 64 * k];
            p0 += dot4(va, w0[k]);
            p2 += dot4(va, w2[k]);
            amax[k] = fmax4(amax[k], va);
        }
        float4 vm = ((const float4*)(mod + (size_t)row * DM))[lane];
        float q0 = dot4(vm, wq0);
        float q2 = dot4(vm, wq2);
        mmax = fmax4(mmax, vm);

        // Wave-level reduce of the 4 dot partials (no __syncthreads).
#pragma unroll
        for (int o = 32; o > 0; o >>= 1) {
            p0 += __shfl_xor(p0, o, 64);
            p2 += __shfl_xor(p2, o, 64);
            q0 += __shfl_xor(q0, o, 64);
            q2 += __shfl_xor(q2, o, 64);
        }
        if (lane == 0) {
            proj0a[row] = p0;
            proj2a[row] = p2;
            proj0m[row] = q0;
            proj2m[row] = q2;
        }
    }

    // Publish per-wave partial maxes: att d = 4*(lane+64k)+{0..3}, mod d-DA = 4*lane+{0..3}
    float4* pr = (float4*)&part[w][0];
#pragma unroll
    for (int k = 0; k < 4; ++k) pr[lane + 64 * k] = amax[k];
    ((float4*)&part[w][DA])[lane] = mmax;
    __syncthreads();

    // Cross-wave max reduce; stride DTOT=1280 ≡ 0 mod 32 banks -> conflict-free.
    for (int d = t; d < DTOT; d += 512) {
        float m = part[0][d];
#pragma unroll
        for (int ww = 1; ww < NW; ++ww) m = fmaxf(m, part[ww][d]);
        pmax[((size_t)b * NCHUNK + ch) * DTOT + d] = m;
    }
}

// K3: one 1024-thread block per output logit (g, b).
__global__ __launch_bounds__(1024) void k_final(
    const float* __restrict__ att, const float* __restrict__ mod,
    const float* __restrict__ Wa, const float* __restrict__ Wm,
    const float* __restrict__ ba, const float* __restrict__ bm,
    const int* __restrict__ gidx, const int* __restrict__ mask,
    const float* __restrict__ proj0a, const float* __restrict__ proj2a,
    const float* __restrict__ proj0m, const float* __restrict__ proj2m,
    const float* __restrict__ pmax,
    float* __restrict__ out)
{
    __shared__ float4 s4v[16];
    __shared__ float s16[16];
    __shared__ float4 pA[4][256];   // 16 KB: per-sub-block att maxes
    __shared__ float  pM[4][256];   // 4 KB: per-sub-block mod maxes
    const int g = blockIdx.x, b = blockIdx.y, t = threadIdx.x;
    const int gi = gidx[b * G + g];

    if (g == 0) {
        // Global row: unmasked sums of proj2, mask count, and max-dot from pmax.
        float sa = 0.f, sm = 0.f, cm = 0.f;
        for (int s = t; s < S; s += 1024) {
            sa += proj2a[b * S + s];
            sm += proj2m[b * S + s];
            cm += (float)mask[b * S + s];
        }
        float gm = 0.f;
        for (int d = t; d < DTOT; d += 1024) {
            float m = -INFINITY;
#pragma unroll
            for (int ch = 0; ch < NCHUNK; ++ch)
                m = fmaxf(m, pmax[((size_t)b * NCHUNK + ch) * DTOT + d]);
            float wgt = (d < DA) ? Wa[DA + d] : Wm[DM + (d - DA)];
            gm += wgt * m;
        }
        float4 r = blockReduceSum4_16(make_float4(sa, sm, cm, gm), s4v);
        if (t == 0) {
            float res = proj0a[b * S + gi] + proj0m[b * S + gi] + r.w +
                        r.x / r.z + r.y / r.z + ba[0] + bm[0];
            out[b * G + 0] = res;
        }
    } else {
        int lo = gi - WIN; if (lo < 0) lo = 0;
        int hi = gi + WIN; if (hi > S - 1) hi = S - 1;

        const int sb = t >> 8;      // sub-block 0..3 (one 256-thread row team)
        const int dt = t & 255;     // float4 column within the row

        // Per-d windowed max (clamped at 0: out-of-window entries contribute 0
        // to the reference's max over x*wmf, and 25 < 512 always leaves zeros).
        // Sub-block sb covers s = lo+sb, lo+sb+4, ... -> serial depth ceil(25/4).
        float4 m4 = make_float4(0.f, 0.f, 0.f, 0.f);
        float mm = 0.f, sa = 0.f, sm = 0.f, cn = 0.f;
        const float4* a4 = (const float4*)att;
        for (int s = lo + sb; s <= hi; s += 4) {
            if (mask[b * S + s] > 0) {
                float4 v = a4[(size_t)(b * S + s) * (DA / 4) + dt];
                m4 = fmax4(m4, v);
                mm = fmaxf(mm, mod[(size_t)(b * S + s) * DM + dt]);
                if (dt == 0) {
                    sa += proj2a[b * S + s];
                    sm += proj2m[b * S + s];
                    cn += 1.f;
                }
            }
        }
        pA[sb][dt] = m4;
        pM[sb][dt] = mm;
        __syncthreads();

        float pa = 0.f, pm = 0.f;
        if (t < 256) {
            float4 mm4 = fmax4(fmax4(pA[0][t], pA[1][t]),
                               fmax4(pA[2][t], pA[3][t]));
            float mmm = fmaxf(fmaxf(pM[0][t], pM[1][t]),
                              fmaxf(pM[2][t], pM[3][t]));
            const float4* W1a4 = (const float4*)(Wa + DA);
            pa = dot4(mm4, W1a4[t]);
            pm = Wm[DM + t] * mmm;
        }
        float4 r = blockReduceSum4_16(make_float4(pa, pm, sa, sm), s4v);
        cn = blockReduceSum_16(cn, s16);
        if (t == 0) {
            float res = proj0a[b * S + gi] + proj0m[b * S + gi] +
                        r.x + r.y + r.z / cn + r.w / cn + ba[0] + bm[0];
            out[b * G + g] = res;
        }
    }
}

extern "C" void kernel_launch(void* const* d_in, const int* in_sizes, int n_in,
                              void* d_out, int out_size, void* d_ws, size_t ws_size,
                              hipStream_t stream) {
    const float* att  = (const float*)d_in[0];
    const float* mod  = (const float*)d_in[1];
    const float* Wa   = (const float*)d_in[2];
    const float* ba   = (const float*)d_in[3];
    const float* Wm   = (const float*)d_in[4];
    const float* bm   = (const float*)d_in[5];
    // d_in[6] = q_enc (unused by reference)
    const int* gidx   = (const int*)d_in[7];
    const int* mask   = (const int*)d_in[8];
    // d_in[9] = q_mask (unused by reference)
    float* out = (float*)d_out;

    // Workspace layout (floats)
    float* ws     = (float*)d_ws;
    float* proj0a = ws;                 // B*S
    float* proj2a = proj0a + B * S;     // B*S
    float* proj0m = proj2a + B * S;     // B*S
    float* proj2m = proj0m + B * S;     // B*S
    float* pmax   = proj2m + B * S;     // B*NCHUNK*DTOT

    k_fused<<<dim3(NCHUNK, B), 512, 0, stream>>>(att, mod, Wa, Wm,
                                                 proj0a, proj2a, proj0m, proj2m,
                                                 pmax);
    k_final<<<dim3(G, B), 1024, 0, stream>>>(att, mod, Wa, Wm, ba, bm, gidx, mask,
                                             proj0a, proj2a, proj0m, proj2m,
                                             pmax, out);
}